// Round 14
// baseline (863.939 us; speedup 1.0000x reference)
//
#include <hip/hip_runtime.h>

// CrossModalHyperedgeInteraction: 3-modality cross-attention, MI355X bf16-MFMA impl.
// R14: attn_k software-pipelined one tile: interleave PV(t-1) 1:1 with QK(t) (independent
// streams) carrying P(t-1) in regs (pbp). Removes the serial QK->exp->PV chain from each
// barrier region. 2 barriers/tile, counted vmcnt(4), dbuf K+V, proven swizzles, XCD-balanced.
// conv_all/proj_fast/proj fallback byte-identical to R13.
// D=512, B=32, K={1024,768,512}, tokOff={0,32768,57344}, tokens 73728.

typedef unsigned short u16;
typedef unsigned int   u32;
typedef __attribute__((ext_vector_type(8))) short vbf8;   // 8 bf16 (4 VGPR) MFMA A/B frag
typedef __attribute__((ext_vector_type(4))) float vf4;    // MFMA C/D frag

#define MFMA(a,b,c) __builtin_amdgcn_mfma_f32_16x16x32_bf16(a,b,c,0,0,0)

__device__ __forceinline__ u16 f2bf(float f){
  u32 x = __float_as_uint(f);
  return (u16)((x + 0x7fffu + ((x >> 16) & 1u)) >> 16);   // RNE bf16
}

__device__ __forceinline__ void gll16(const void* g, void* l){
  __builtin_amdgcn_global_load_lds(
      (const __attribute__((address_space(1))) u32*)g,
      (__attribute__((address_space(3))) u32*)l, 16, 0, 0);
}

// ---------------- kernel 1a: W fp32 -> bf16 (fallback path) ----------------
__global__ void wconv_k(const float* __restrict__ Wq, const float* __restrict__ Wk,
                        const float* __restrict__ Wv, const float* __restrict__ Wo,
                        u16* __restrict__ Wbf){
  int i = blockIdx.x * 256 + threadIdx.x;
  int w = i >> 16;
  int off = (i & 65535) << 2;
  const float* src = (w == 0) ? Wq : (w == 1) ? Wk : (w == 2) ? Wv : Wo;
  float4 v = *(const float4*)(src + off);
  u32 lo = (u32)f2bf(v.x) | ((u32)f2bf(v.y) << 16);
  u32 hi = (u32)f2bf(v.z) | ((u32)f2bf(v.w) << 16);
  uint2 p; p.x = lo; p.y = hi;
  *(uint2*)(Wbf + (w << 18) + off) = p;
}

// ---------------- kernel 1b: W + E fp32 -> bf16 (fast path) ----------------
__global__ void conv_all_k(const float* __restrict__ E0, const float* __restrict__ E1,
                           const float* __restrict__ E2,
                           const float* __restrict__ Wq, const float* __restrict__ Wk,
                           const float* __restrict__ Wv, const float* __restrict__ Wo,
                           u16* __restrict__ Wbf, u16* __restrict__ Eb){
  const size_t base = ((size_t)blockIdx.x * 256 + threadIdx.x) * 8;
  const float* src;
  u16* dst;
  if (base < (1u << 20)){
    int w = (int)(base >> 18), off = (int)(base & 262143);
    src = ((w == 0) ? Wq : (w == 1) ? Wk : (w == 2) ? Wv : Wo) + off;
    dst = Wbf + (w << 18) + off;
  } else {
    size_t e = base - (1u << 20);
    int token = (int)(e >> 9), d = (int)(e & 511);
    const float* Es = (token < 32768) ? (E0 + (size_t)token * 512)
                    : (token < 57344) ? (E1 + (size_t)(token - 32768) * 512)
                                      : (E2 + (size_t)(token - 57344) * 512);
    src = Es + d;
    dst = Eb + (size_t)token * 512 + d;
  }
  float4 a = *(const float4*)src;
  float4 b = *(const float4*)(src + 4);
  int4 p;
  p.x = (int)((u32)f2bf(a.x) | ((u32)f2bf(a.y) << 16));
  p.y = (int)((u32)f2bf(a.z) | ((u32)f2bf(a.w) << 16));
  p.z = (int)((u32)f2bf(b.x) | ((u32)f2bf(b.y) << 16));
  p.w = (int)((u32)f2bf(b.z) | ((u32)f2bf(b.w) << 16));
  *(int4*)dst = p;
}

// ---------------- kernel 2a: unified projection GEMM, pure gll16 (fast path) ----------------
__global__ void __launch_bounds__(256, 2) proj_fast_k(
    const u16* __restrict__ Eb, const u16* __restrict__ Wbf,
    const float* __restrict__ bq, const float* __restrict__ bk,
    const float* __restrict__ bv, const float* __restrict__ bo,
    u16* __restrict__ Qb, u16* __restrict__ Kb, u16* __restrict__ Vtb,
    float* __restrict__ outF)
{
  __shared__ __align__(16) char smem[65536];   // A dbuf 2x16KB @0 | B dbuf 2x16KB @32768

  const int lin = blockIdx.x;
  const int swz = (lin & 7) * 1152 + (lin >> 3);     // XCD-chunked (uniform work/block)
  const int mt = swz >> 4, nt = swz & 15;
  const int widx = nt >> 2, colBase = (nt & 3) * 128;
  const int t0 = mt * 128;
  const int mod = (t0 >= 57344) ? 2 : (t0 >= 32768) ? 1 : 0;
  const int tokOffM = (mod == 0) ? 0 : (mod == 1) ? 32768 : 57344;
  const int Km = (mod == 0) ? 1024 : (mod == 1) ? 768 : 512;
  const float* bias = (widx == 0) ? bq : (widx == 1) ? bk : (widx == 2) ? bv : bo;

  const int tid = threadIdx.x, wv = tid >> 6, l = tid & 63, g = l >> 4, c = l & 15;
  const int wm = wv >> 1, wn = wv & 1;

  vf4 acc[4][4];
  #pragma unroll
  for (int mi = 0; mi < 4; ++mi)
    #pragma unroll
    for (int ni = 0; ni < 4; ++ni) acc[mi][ni] = (vf4){0.f, 0.f, 0.f, 0.f};

  auto stage = [&](int kt, int buf){                 // 8 gll16: A tile + B tile
    char* ad = smem + buf * 16384;
    char* bd = smem + 32768 + buf * 16384;
    #pragma unroll
    for (int p = 0; p < 4; ++p){
      int t = p * 256 + tid, row = t >> 3, sl = t & 7;
      int so = ((sl ^ (row & 7)) << 3);
      gll16(Eb + (size_t)(t0 + row) * 512 + kt * 64 + so, ad + t * 16);
      gll16(Wbf + (size_t)(nt * 128 + row) * 512 + kt * 64 + so, bd + t * 16);
    }
  };

  stage(0, 0);
  for (int kt = 0; kt < 8; ++kt){
    const int cur = kt & 1;
    asm volatile("s_waitcnt vmcnt(0)" ::: "memory");
    __builtin_amdgcn_s_barrier();
    asm volatile("" ::: "memory");
    if (kt + 1 < 8) stage(kt + 1, cur ^ 1);

    const char* A  = smem + cur * 16384;
    const char* Bl = smem + 32768 + cur * 16384;
    #pragma unroll
    for (int kh = 0; kh < 2; ++kh){
      vbf8 af[4], bf[4];
      #pragma unroll
      for (int mi = 0; mi < 4; ++mi){
        int row = wm * 64 + mi * 16 + c;
        af[mi] = *(const vbf8*)(A + row * 128 + ((((kh << 2) + g) ^ (row & 7)) << 4));
      }
      #pragma unroll
      for (int ni = 0; ni < 4; ++ni){
        int row = wn * 64 + ni * 16 + c;
        bf[ni] = *(const vbf8*)(Bl + row * 128 + ((((kh << 2) + g) ^ (row & 7)) << 4));
      }
      #pragma unroll
      for (int mi = 0; mi < 4; ++mi)
        #pragma unroll
        for (int ni = 0; ni < 4; ++ni)
          acc[mi][ni] = MFMA(af[mi], bf[ni], acc[mi][ni]);
    }
    asm volatile("" ::: "memory");
  }
  __syncthreads();

  if (widx == 2){
    u16* T = (u16*)smem;                                  // [128 e][136]
    #pragma unroll
    for (int ni = 0; ni < 4; ++ni){
      int el = wn * 64 + ni * 16 + c;
      float bb = bias[colBase + el];
      #pragma unroll
      for (int mi = 0; mi < 4; ++mi)
        #pragma unroll
        for (int r = 0; r < 4; ++r){
          int tk = wm * 64 + mi * 16 + g * 4 + r;
          T[el * 136 + tk] = f2bf(acc[mi][ni][r] + bb);
        }
    }
    __syncthreads();
    const int b = (t0 - tokOffM) / Km, tokl = (t0 - tokOffM) - b * Km;
    const size_t vbase = (size_t)tokOffM * 512 + (size_t)b * 512 * Km + tokl;
    #pragma unroll
    for (int it = 0; it < 8; ++it){
      int flat = it * 256 + tid;
      int el = flat >> 4, tg = flat & 15;
      const u16* tp = T + el * 136 + tg * 8;
      int4 pk;
      pk.x = (int)((u32)tp[0] | ((u32)tp[1] << 16));
      pk.y = (int)((u32)tp[2] | ((u32)tp[3] << 16));
      pk.z = (int)((u32)tp[4] | ((u32)tp[5] << 16));
      pk.w = (int)((u32)tp[6] | ((u32)tp[7] << 16));
      *(int4*)(Vtb + vbase + (size_t)(colBase + el) * Km + tg * 8) = pk;
    }
  } else {
    const float scale = (widx == 0) ? 0.04419417382415922f : 1.0f;   // 1/sqrt(512) into Q
    #pragma unroll
    for (int ni = 0; ni < 4; ++ni){
      int col = colBase + wn * 64 + ni * 16 + c;
      float bb = bias[col];
      #pragma unroll
      for (int mi = 0; mi < 4; ++mi)
        #pragma unroll
        for (int r = 0; r < 4; ++r){
          int token = t0 + wm * 64 + mi * 16 + g * 4 + r;
          float val = (acc[mi][ni][r] + bb) * scale;
          size_t idx = (size_t)token * 512 + col;
          if (widx == 3)      outF[idx] = val;
          else if (widx == 0) Qb[idx] = f2bf(val);
          else                Kb[idx] = f2bf(val);
        }
    }
  }
}

// ---------------- kernel 2b: R12 proj (fallback when ws too small) ----------------
__global__ void __launch_bounds__(256, 2) proj_k(
    const float* __restrict__ E0, const float* __restrict__ E1, const float* __restrict__ E2,
    const u16* __restrict__ Wbf,
    const float* __restrict__ bq, const float* __restrict__ bk,
    const float* __restrict__ bv, const float* __restrict__ bo,
    u16* __restrict__ Qb, u16* __restrict__ Kb, u16* __restrict__ Vtb,
    float* __restrict__ outF)
{
  __shared__ __align__(16) char smem[65536];

  const int lin = blockIdx.x;
  const int swz = (lin & 7) * 1152 + (lin >> 3);
  const int mt = swz >> 4, nt = swz & 15;
  const int widx = nt >> 2, colBase = (nt & 3) * 128;
  const int t0 = mt * 128;
  const int mod = (t0 >= 57344) ? 2 : (t0 >= 32768) ? 1 : 0;
  const int tokOffM = (mod == 0) ? 0 : (mod == 1) ? 32768 : 57344;
  const int Km = (mod == 0) ? 1024 : (mod == 1) ? 768 : 512;
  const float* E = (mod == 0) ? E0 : (mod == 1) ? E1 : E2;
  const float* bias = (widx == 0) ? bq : (widx == 1) ? bk : (widx == 2) ? bv : bo;

  const int tid = threadIdx.x, wv = tid >> 6, l = tid & 63, g = l >> 4, c = l & 15;
  const int wm = wv >> 1, wn = wv & 1;

  float4 ar[4][2];
  vf4 acc[4][4];
  #pragma unroll
  for (int mi = 0; mi < 4; ++mi)
    #pragma unroll
    for (int ni = 0; ni < 4; ++ni) acc[mi][ni] = (vf4){0.f, 0.f, 0.f, 0.f};

  auto loadA = [&](int kt){
    #pragma unroll
    for (int p = 0; p < 4; ++p){
      int t = p * 256 + tid, row = t >> 3, sl = t & 7;
      const float* s = E + (size_t)(t0 - tokOffM + row) * 512 + kt * 64 + ((sl ^ (row & 7)) << 3);
      ar[p][0] = *(const float4*)s;
      ar[p][1] = *(const float4*)(s + 4);
    }
  };
  auto glB = [&](int kt, int nxt){
    char* dst = smem + 32768 + nxt * 16384;
    #pragma unroll
    for (int p = 0; p < 4; ++p){
      int t = p * 256 + tid, row = t >> 3, sl = t & 7;
      gll16(Wbf + (size_t)(nt * 128 + row) * 512 + kt * 64 + ((sl ^ (row & 7)) << 3),
            dst + t * 16);
    }
  };
  auto writeA = [&](int nxt){
    char* dst = smem + nxt * 16384;
    #pragma unroll
    for (int p = 0; p < 4; ++p){
      int t = p * 256 + tid;
      int4 pk;
      pk.x = (int)((u32)f2bf(ar[p][0].x) | ((u32)f2bf(ar[p][0].y) << 16));
      pk.y = (int)((u32)f2bf(ar[p][0].z) | ((u32)f2bf(ar[p][0].w) << 16));
      pk.z = (int)((u32)f2bf(ar[p][1].x) | ((u32)f2bf(ar[p][1].y) << 16));
      pk.w = (int)((u32)f2bf(ar[p][1].z) | ((u32)f2bf(ar[p][1].w) << 16));
      *(int4*)(dst + t * 16) = pk;
    }
  };

  loadA(0); glB(0, 0);
  asm volatile("s_waitcnt vmcnt(4)" ::: "memory");
  writeA(0);
  loadA(1);

  #pragma unroll
  for (int kt = 0; kt < 8; ++kt){
    const int cur = kt & 1;
    if (kt == 7) asm volatile("s_waitcnt vmcnt(0)" ::: "memory");
    else         asm volatile("s_waitcnt vmcnt(8)" ::: "memory");
    asm volatile("s_waitcnt lgkmcnt(0)" ::: "memory");
    __builtin_amdgcn_s_barrier();
    asm volatile("" ::: "memory");
    if (kt + 1 < 8) glB(kt + 1, cur ^ 1);

    const char* A  = smem + cur * 16384;
    const char* Bl = smem + 32768 + cur * 16384;
    #pragma unroll
    for (int kh = 0; kh < 2; ++kh){
      vbf8 af[4], bf[4];
      #pragma unroll
      for (int mi = 0; mi < 4; ++mi){
        int row = wm * 64 + mi * 16 + c;
        af[mi] = *(const vbf8*)(A + row * 128 + ((((kh << 2) + g) ^ (row & 7)) << 4));
      }
      #pragma unroll
      for (int ni = 0; ni < 4; ++ni){
        int row = wn * 64 + ni * 16 + c;
        bf[ni] = *(const vbf8*)(Bl + row * 128 + ((((kh << 2) + g) ^ (row & 7)) << 4));
      }
      #pragma unroll
      for (int mi = 0; mi < 4; ++mi)
        #pragma unroll
        for (int ni = 0; ni < 4; ++ni)
          acc[mi][ni] = MFMA(af[mi], bf[ni], acc[mi][ni]);
    }

    if (kt + 1 < 8){
      asm volatile("s_waitcnt vmcnt(4)" ::: "memory");
      writeA(cur ^ 1);
      if (kt + 2 < 8) loadA(kt + 2);
    }
  }
  __syncthreads();

  if (widx == 2){
    u16* T = (u16*)smem;
    #pragma unroll
    for (int ni = 0; ni < 4; ++ni){
      int el = wn * 64 + ni * 16 + c;
      float bb = bias[colBase + el];
      #pragma unroll
      for (int mi = 0; mi < 4; ++mi)
        #pragma unroll
        for (int r = 0; r < 4; ++r){
          int tk = wm * 64 + mi * 16 + g * 4 + r;
          T[el * 136 + tk] = f2bf(acc[mi][ni][r] + bb);
        }
    }
    __syncthreads();
    const int b = (t0 - tokOffM) / Km, tokl = (t0 - tokOffM) - b * Km;
    const size_t vbase = (size_t)tokOffM * 512 + (size_t)b * 512 * Km + tokl;
    #pragma unroll
    for (int it = 0; it < 8; ++it){
      int flat = it * 256 + tid;
      int el = flat >> 4, tg = flat & 15;
      const u16* tp = T + el * 136 + tg * 8;
      int4 pk;
      pk.x = (int)((u32)tp[0] | ((u32)tp[1] << 16));
      pk.y = (int)((u32)tp[2] | ((u32)tp[3] << 16));
      pk.z = (int)((u32)tp[4] | ((u32)tp[5] << 16));
      pk.w = (int)((u32)tp[6] | ((u32)tp[7] << 16));
      *(int4*)(Vtb + vbase + (size_t)(colBase + el) * Km + tg * 8) = pk;
    }
  } else {
    const float scale = (widx == 0) ? 0.04419417382415922f : 1.0f;
    #pragma unroll
    for (int ni = 0; ni < 4; ++ni){
      int col = colBase + wn * 64 + ni * 16 + c;
      float bb = bias[col];
      #pragma unroll
      for (int mi = 0; mi < 4; ++mi)
        #pragma unroll
        for (int r = 0; r < 4; ++r){
          int token = t0 + wm * 64 + mi * 16 + g * 4 + r;
          float val = (acc[mi][ni][r] + bb) * scale;
          size_t idx = (size_t)token * 512 + col;
          if (widx == 3)      outF[idx] = val;
          else if (widx == 0) Qb[idx] = f2bf(val);
          else                Kb[idx] = f2bf(val);
        }
    }
  }
}

// ---------------- kernel 3: cross attention (PV(t-1) ∥ QK(t) pipelined) ----------------
// 576 x 512 thr, KVBLK=32, dbuf K+V. Body t: vmcnt(4)[K(t),V(t-1) landed] -> barrier1 ->
// stageK(t+1) -> interleaved [QK(t) + PV(t-1) via reg-carried pbp] -> exp(t)->pbp ->
// barrier2 -> stageV(t+1). Tail PV(NT-1) after loop. Same barrier count as R12.
__global__ void __launch_bounds__(512, 2) attn_k(
    const u16* __restrict__ Qb, const u16* __restrict__ Kb,
    const u16* __restrict__ Vtb, float* __restrict__ outF)
{
  __shared__ __align__(16) char smem[131072];  // K dbuf 2x32KB @0 | Vt dbuf 2x32KB @65536

  // XCD-balanced: 576 = 8 xcd * 72 (32 m0 | 24 m1 | 16 m2), y-locality per xcd
  const int lin = blockIdx.x;
  const int xcd = lin & 7, pos = lin >> 3;
  int m, y, xq;
  if (pos < 32)      { m = 0; y = xcd * 4 + (pos >> 3); xq = pos & 7; }
  else if (pos < 56) { int p = pos - 32; int yl = p / 6; m = 1; y = xcd * 4 + yl; xq = p - yl * 6; }
  else               { int p = pos - 56; m = 2; y = xcd * 4 + (p >> 2); xq = p & 3; }

  const int Km = (m == 0) ? 1024 : (m == 1) ? 768 : 512;
  const int tokOffM = (m == 0) ? 0 : (m == 1) ? 32768 : 57344;

  const int tid = threadIdx.x, wv = tid >> 6, l = tid & 63, g = l >> 4, c = l & 15;
  const int qbase = tokOffM + y * Km + xq * 128 + wv * 16;

  const int kperm = (c >> 2) * 8 + (c & 3);
  const int chx   = c >> 2;
  const int kb_lane = kperm * 1024 + ((g ^ (c & 3)) << 4);
  const int vb_lane = c * 64 + ((g ^ ((c >> 1) & 3)) << 4);

  vbf8 qf[16];
  {
    const u16* qp = Qb + (size_t)(qbase + c) * 512 + g * 8;
    #pragma unroll
    for (int ch = 0; ch < 16; ++ch) qf[ch] = *(const vbf8*)(qp + ch * 32);
  }

  vf4 acc[32];
  #pragma unroll
  for (int ch = 0; ch < 32; ++ch) acc[ch] = (vf4){0.f, 0.f, 0.f, 0.f};
  float lp = 0.f;

  for (int srcI = 0; srcI < 2; ++srcI){
    const int n = (srcI == 0) ? ((m == 0) ? 1 : 0) : ((m == 2) ? 1 : 2);
    const int Kn = (n == 0) ? 1024 : (n == 1) ? 768 : 512;
    const int NT = Kn >> 5;
    const int tokOffN = (n == 0) ? 0 : (n == 1) ? 32768 : 57344;
    const size_t kRow0 = (size_t)(tokOffN + y * Kn);
    const size_t vBase = (size_t)tokOffN * 512 + (size_t)y * 512 * Kn;

    auto stageK = [&](int kt, int buf){
      char* kd = smem + buf * 32768;
      const size_t kB = (kRow0 + kt * 32) * 512;
      #pragma unroll
      for (int p = 0; p < 4; ++p){
        int t = p * 512 + tid;
        int key = t >> 6, sl = t & 63;
        int F = (key & 3) | (((key >> 3) & 3) << 2);
        gll16(Kb + kB + (size_t)key * 512 + ((sl ^ F) << 3), kd + t * 16);
      }
    };
    auto stageV = [&](int kt, int buf){
      char* vd = smem + 65536 + buf * 32768;
      #pragma unroll
      for (int p = 0; p < 4; ++p){
        int t = p * 512 + tid;
        int d = t >> 2, sl = t & 3;
        gll16(Vtb + vBase + (size_t)d * Kn + kt * 32 + ((sl ^ ((d >> 1) & 3)) << 3),
              vd + t * 16);
      }
    };

    vbf8 pbp;                                        // P(t-1), reg-carried
    auto exppack = [&](vf4 s0, vf4 s1){
      float e00 = __expf(s0[0]), e01 = __expf(s0[1]), e02 = __expf(s0[2]), e03 = __expf(s0[3]);
      float e10 = __expf(s1[0]), e11 = __expf(s1[1]), e12 = __expf(s1[2]), e13 = __expf(s1[3]);
      lp += (e00 + e01 + e02 + e03) + (e10 + e11 + e12 + e13);
      vbf8 pb;
      pb[0]=(short)f2bf(e00); pb[1]=(short)f2bf(e01); pb[2]=(short)f2bf(e02); pb[3]=(short)f2bf(e03);
      pb[4]=(short)f2bf(e10); pb[5]=(short)f2bf(e11); pb[6]=(short)f2bf(e12); pb[7]=(short)f2bf(e13);
      pbp = pb;
    };

    stageK(0, 0); stageV(0, 0);

    // ---- body 0: QK(0) only ----
    asm volatile("s_waitcnt vmcnt(4)" ::: "memory");      // K(0) landed (V(0) may fly)
    __builtin_amdgcn_s_barrier();
    asm volatile("" ::: "memory");
    if (NT > 1) stageK(1, 1);
    {
      const char* kbuf = smem;
      vf4 s0a = (vf4){0.f,0.f,0.f,0.f}, s0b = (vf4){0.f,0.f,0.f,0.f};
      vf4 s1a = (vf4){0.f,0.f,0.f,0.f}, s1b = (vf4){0.f,0.f,0.f,0.f};
      #pragma unroll
      for (int ch = 0; ch < 8; ++ch){
        const char* pa0 = kbuf + kb_lane + ((ch ^ chx) << 6);
        const char* pa1 = kbuf + kb_lane + (((ch + 8) ^ chx) << 6);
        vbf8 ka0  = *(const vbf8*)(pa0);
        vbf8 ka0h = *(const vbf8*)(pa0 + 4096);
        vbf8 ka1  = *(const vbf8*)(pa1);
        vbf8 ka1h = *(const vbf8*)(pa1 + 4096);
        s0a = MFMA(ka0,  qf[ch],     s0a);
        s1a = MFMA(ka0h, qf[ch],     s1a);
        s0b = MFMA(ka1,  qf[ch + 8], s0b);
        s1b = MFMA(ka1h, qf[ch + 8], s1b);
      }
      exppack(s0a + s0b, s1a + s1b);
    }
    asm volatile("" ::: "memory");
    __builtin_amdgcn_s_barrier();
    asm volatile("" ::: "memory");
    if (NT > 1) stageV(1, 1);

    // ---- bodies 1..NT-1: QK(t) ∥ PV(t-1) ----
    for (int kt = 1; kt < NT; ++kt){
      const int cur = kt & 1;
      asm volatile("s_waitcnt vmcnt(4)" ::: "memory");    // K(kt), V(kt-1) landed
      __builtin_amdgcn_s_barrier();                       // barrier1
      asm volatile("" ::: "memory");
      if (kt + 1 < NT) stageK(kt + 1, cur ^ 1);

      const char* kbuf = smem + cur * 32768;
      const char* vbuf = smem + 65536 + (cur ^ 1) * 32768;   // V(kt-1)
      vf4 s0a = (vf4){0.f,0.f,0.f,0.f}, s0b = (vf4){0.f,0.f,0.f,0.f};
      vf4 s1a = (vf4){0.f,0.f,0.f,0.f}, s1b = (vf4){0.f,0.f,0.f,0.f};
      #pragma unroll
      for (int ch = 0; ch < 8; ++ch){
        const char* pa0 = kbuf + kb_lane + ((ch ^ chx) << 6);
        const char* pa1 = kbuf + kb_lane + (((ch + 8) ^ chx) << 6);
        vbf8 ka0  = *(const vbf8*)(pa0);
        vbf8 ka0h = *(const vbf8*)(pa0 + 4096);
        vbf8 ka1  = *(const vbf8*)(pa1);
        vbf8 ka1h = *(const vbf8*)(pa1 + 4096);
        s0a = MFMA(ka0,  qf[ch],     s0a);
        s1a = MFMA(ka0h, qf[ch],     s1a);
        s0b = MFMA(ka1,  qf[ch + 8], s0b);
        s1b = MFMA(ka1h, qf[ch + 8], s1b);
        #pragma unroll
        for (int r = 0; r < 4; ++r){                      // PV(kt-1), independent stream
          vbf8 va = *(const vbf8*)(vbuf + vb_lane + (ch * 4 + r) * 1024);
          acc[ch * 4 + r] = MFMA(va, pbp, acc[ch * 4 + r]);
        }
      }
      exppack(s0a + s0b, s1a + s1b);
      asm volatile("" ::: "memory");
      __builtin_amdgcn_s_barrier();                       // barrier2: PV(kt-1)+QK(kt) reads done
      asm volatile("" ::: "memory");
      if (kt + 1 < NT) stageV(kt + 1, cur ^ 1);
    }

    // ---- tail: PV(NT-1) ----
    asm volatile("s_waitcnt vmcnt(0)" ::: "memory");      // V(NT-1) landed
    {
      const char* vbuf = smem + 65536 + ((NT - 1) & 1) * 32768;
      #pragma unroll
      for (int ch = 0; ch < 32; ++ch){
        vbf8 va = *(const vbf8*)(vbuf + vb_lane + ch * 1024);
        acc[ch] = MFMA(va, pbp, acc[ch]);
      }
    }
    asm volatile("" ::: "memory");
    __syncthreads();                                      // reads done before next source

    // ---- finalize source: denominator over 4 g-groups; merge into d_out ----
    float t = lp;
    t += __shfl_xor(t, 16);
    t += __shfl_xor(t, 32);
    const float w = 1.0f / t;
    lp = 0.f;
    float* op = outF + (size_t)(qbase + c) * 512 + g * 4;
    #pragma unroll
    for (int ch = 0; ch < 32; ++ch){
      float4* p4 = (float4*)(op + ch * 16);
      float4 v = *p4;
      v.x += acc[ch][0] * w; v.y += acc[ch][1] * w;
      v.z += acc[ch][2] * w; v.w += acc[ch][3] * w;
      if (srcI == 1){
        v.x = fmaxf(v.x, 0.f); v.y = fmaxf(v.y, 0.f);
        v.z = fmaxf(v.z, 0.f); v.w = fmaxf(v.w, 0.f);
      }
      *p4 = v;
      acc[ch] = (vf4){0.f, 0.f, 0.f, 0.f};
    }
  }
}

// ---------------- host launcher ----------------
extern "C" void kernel_launch(void* const* d_in, const int* in_sizes, int n_in,
                              void* d_out, int out_size, void* d_ws, size_t ws_size,
                              hipStream_t stream){
  const float* E0 = (const float*)d_in[0];
  const float* E1 = (const float*)d_in[1];
  const float* E2 = (const float*)d_in[2];
  const float* Wq = (const float*)d_in[3];
  const float* bq = (const float*)d_in[4];
  const float* Wk = (const float*)d_in[5];
  const float* bk = (const float*)d_in[6];
  const float* Wv = (const float*)d_in[7];
  const float* bv = (const float*)d_in[8];
  const float* Wo = (const float*)d_in[9];
  const float* bo = (const float*)d_in[10];
  float* outF = (float*)d_out;

  char* ws = (char*)d_ws;
  const size_t SZ = 75497472u;                 // 73728*512*2 bytes (bf16)
  u16* Wbf = (u16*)ws;                         // 2 MB, [2048][512]
  u16* Qb  = (u16*)(ws + (size_t)(2u << 20));
  u16* Kb  = (u16*)(ws + (size_t)(2u << 20) + SZ);
  u16* Vtb = (u16*)(ws + (size_t)(2u << 20) + 2 * SZ);
  u16* Eb  = (u16*)(ws + (size_t)(2u << 20) + 3 * SZ);   // fast path only
  const size_t NEED_FAST = (size_t)(2u << 20) + 4 * SZ;  // ~290 MB

  if (ws_size >= NEED_FAST){
    conv_all_k<<<dim3(18944), dim3(256), 0, stream>>>(E0, E1, E2, Wq, Wk, Wv, Wo, Wbf, Eb);
    proj_fast_k<<<dim3(9216), dim3(256), 0, stream>>>(Eb, Wbf, bq, bk, bv, bo,
                                                      Qb, Kb, Vtb, outF);
  } else {
    wconv_k<<<dim3(1024), dim3(256), 0, stream>>>(Wq, Wk, Wv, Wo, Wbf);
    proj_k<<<dim3(9216), dim3(256), 0, stream>>>(E0, E1, E2, Wbf, bq, bk, bv, bo,
                                                 Qb, Kb, Vtb, outF);
  }
  attn_k<<<dim3(576), dim3(512), 0, stream>>>(Qb, Kb, Vtb, outF);
}

// Round 15
// 741.846 us; speedup vs baseline: 1.1646x; 1.1646x over previous
//
#include <hip/hip_runtime.h>

// CrossModalHyperedgeInteraction: 3-modality cross-attention, MI355X bf16-MFMA impl.
// R15: attn_k reverted to R12-exact (R14's PV∥QK interleave regressed 493->570: fused
// streams over-coupled lgkmcnt) + s_setprio around MFMA clusters (T5, low-risk probe).
// proj_fast: loop-invariant stage addressing. conv_all/proj fallback unchanged.
// D=512, B=32, K={1024,768,512}, tokOff={0,32768,57344}, tokens 73728.

typedef unsigned short u16;
typedef unsigned int   u32;
typedef __attribute__((ext_vector_type(8))) short vbf8;   // 8 bf16 (4 VGPR) MFMA A/B frag
typedef __attribute__((ext_vector_type(4))) float vf4;    // MFMA C/D frag

#define MFMA(a,b,c) __builtin_amdgcn_mfma_f32_16x16x32_bf16(a,b,c,0,0,0)

__device__ __forceinline__ u16 f2bf(float f){
  u32 x = __float_as_uint(f);
  return (u16)((x + 0x7fffu + ((x >> 16) & 1u)) >> 16);   // RNE bf16
}

__device__ __forceinline__ void gll16(const void* g, void* l){
  __builtin_amdgcn_global_load_lds(
      (const __attribute__((address_space(1))) u32*)g,
      (__attribute__((address_space(3))) u32*)l, 16, 0, 0);
}

// ---------------- kernel 1a: W fp32 -> bf16 (fallback path) ----------------
__global__ void wconv_k(const float* __restrict__ Wq, const float* __restrict__ Wk,
                        const float* __restrict__ Wv, const float* __restrict__ Wo,
                        u16* __restrict__ Wbf){
  int i = blockIdx.x * 256 + threadIdx.x;
  int w = i >> 16;
  int off = (i & 65535) << 2;
  const float* src = (w == 0) ? Wq : (w == 1) ? Wk : (w == 2) ? Wv : Wo;
  float4 v = *(const float4*)(src + off);
  u32 lo = (u32)f2bf(v.x) | ((u32)f2bf(v.y) << 16);
  u32 hi = (u32)f2bf(v.z) | ((u32)f2bf(v.w) << 16);
  uint2 p; p.x = lo; p.y = hi;
  *(uint2*)(Wbf + (w << 18) + off) = p;
}

// ---------------- kernel 1b: W + E fp32 -> bf16 (fast path) ----------------
__global__ void conv_all_k(const float* __restrict__ E0, const float* __restrict__ E1,
                           const float* __restrict__ E2,
                           const float* __restrict__ Wq, const float* __restrict__ Wk,
                           const float* __restrict__ Wv, const float* __restrict__ Wo,
                           u16* __restrict__ Wbf, u16* __restrict__ Eb){
  const size_t base = ((size_t)blockIdx.x * 256 + threadIdx.x) * 8;
  const float* src;
  u16* dst;
  if (base < (1u << 20)){
    int w = (int)(base >> 18), off = (int)(base & 262143);
    src = ((w == 0) ? Wq : (w == 1) ? Wk : (w == 2) ? Wv : Wo) + off;
    dst = Wbf + (w << 18) + off;
  } else {
    size_t e = base - (1u << 20);
    int token = (int)(e >> 9), d = (int)(e & 511);
    const float* Es = (token < 32768) ? (E0 + (size_t)token * 512)
                    : (token < 57344) ? (E1 + (size_t)(token - 32768) * 512)
                                      : (E2 + (size_t)(token - 57344) * 512);
    src = Es + d;
    dst = Eb + (size_t)token * 512 + d;
  }
  float4 a = *(const float4*)src;
  float4 b = *(const float4*)(src + 4);
  int4 p;
  p.x = (int)((u32)f2bf(a.x) | ((u32)f2bf(a.y) << 16));
  p.y = (int)((u32)f2bf(a.z) | ((u32)f2bf(a.w) << 16));
  p.z = (int)((u32)f2bf(b.x) | ((u32)f2bf(b.y) << 16));
  p.w = (int)((u32)f2bf(b.z) | ((u32)f2bf(b.w) << 16));
  *(int4*)dst = p;
}

// ---------------- kernel 2a: unified projection GEMM, pure gll16 (fast path) ----------------
__global__ void __launch_bounds__(256, 2) proj_fast_k(
    const u16* __restrict__ Eb, const u16* __restrict__ Wbf,
    const float* __restrict__ bq, const float* __restrict__ bk,
    const float* __restrict__ bv, const float* __restrict__ bo,
    u16* __restrict__ Qb, u16* __restrict__ Kb, u16* __restrict__ Vtb,
    float* __restrict__ outF)
{
  __shared__ __align__(16) char smem[65536];   // A dbuf 2x16KB @0 | B dbuf 2x16KB @32768

  const int lin = blockIdx.x;
  const int swz = (lin & 7) * 1152 + (lin >> 3);     // XCD-chunked (uniform work/block)
  const int mt = swz >> 4, nt = swz & 15;
  const int widx = nt >> 2, colBase = (nt & 3) * 128;
  const int t0 = mt * 128;
  const int mod = (t0 >= 57344) ? 2 : (t0 >= 32768) ? 1 : 0;
  const int tokOffM = (mod == 0) ? 0 : (mod == 1) ? 32768 : 57344;
  const int Km = (mod == 0) ? 1024 : (mod == 1) ? 768 : 512;
  const float* bias = (widx == 0) ? bq : (widx == 1) ? bk : (widx == 2) ? bv : bo;

  const int tid = threadIdx.x, wv = tid >> 6, l = tid & 63, g = l >> 4, c = l & 15;
  const int wm = wv >> 1, wn = wv & 1;

  // loop-invariant stage addressing: only kt*64 varies per step
  const int trow = tid >> 3, tsl = tid & 7;
  const int so = ((tsl ^ (trow & 7)) << 3);
  const u16* aSrc = Eb + (size_t)(t0 + trow) * 512 + so;             // + p*32*512 + kt*64
  const u16* bSrc = Wbf + (size_t)(nt * 128 + trow) * 512 + so;

  vf4 acc[4][4];
  #pragma unroll
  for (int mi = 0; mi < 4; ++mi)
    #pragma unroll
    for (int ni = 0; ni < 4; ++ni) acc[mi][ni] = (vf4){0.f, 0.f, 0.f, 0.f};

  auto stage = [&](int kt, int buf){                 // 8 gll16: A tile + B tile
    char* ad = smem + buf * 16384 + tid * 16;
    char* bd = smem + 32768 + buf * 16384 + tid * 16;
    const int ko = kt * 64;
    #pragma unroll
    for (int p = 0; p < 4; ++p){
      gll16(aSrc + (size_t)p * 16384 + ko, ad + p * 4096);
      gll16(bSrc + (size_t)p * 16384 + ko, bd + p * 4096);
    }
  };

  stage(0, 0);
  for (int kt = 0; kt < 8; ++kt){
    const int cur = kt & 1;
    asm volatile("s_waitcnt vmcnt(0)" ::: "memory"); // stage(kt) landed (issued 1 iter ago)
    __builtin_amdgcn_s_barrier();                    // all waves done reading buf[cur^1]
    asm volatile("" ::: "memory");
    if (kt + 1 < 8) stage(kt + 1, cur ^ 1);          // in flight across MFMA(kt)

    const char* A  = smem + cur * 16384;
    const char* Bl = smem + 32768 + cur * 16384;
    __builtin_amdgcn_s_setprio(1);
    #pragma unroll
    for (int kh = 0; kh < 2; ++kh){
      vbf8 af[4], bf[4];
      #pragma unroll
      for (int mi = 0; mi < 4; ++mi){
        int row = wm * 64 + mi * 16 + c;
        af[mi] = *(const vbf8*)(A + row * 128 + ((((kh << 2) + g) ^ (row & 7)) << 4));
      }
      #pragma unroll
      for (int ni = 0; ni < 4; ++ni){
        int row = wn * 64 + ni * 16 + c;
        bf[ni] = *(const vbf8*)(Bl + row * 128 + ((((kh << 2) + g) ^ (row & 7)) << 4));
      }
      #pragma unroll
      for (int mi = 0; mi < 4; ++mi)
        #pragma unroll
        for (int ni = 0; ni < 4; ++ni)
          acc[mi][ni] = MFMA(af[mi], bf[ni], acc[mi][ni]);
    }
    __builtin_amdgcn_s_setprio(0);
    asm volatile("" ::: "memory");
  }
  __syncthreads();

  if (widx == 2){
    u16* T = (u16*)smem;                                  // [128 e][136]
    #pragma unroll
    for (int ni = 0; ni < 4; ++ni){
      int el = wn * 64 + ni * 16 + c;
      float bb = bias[colBase + el];
      #pragma unroll
      for (int mi = 0; mi < 4; ++mi)
        #pragma unroll
        for (int r = 0; r < 4; ++r){
          int tk = wm * 64 + mi * 16 + g * 4 + r;
          T[el * 136 + tk] = f2bf(acc[mi][ni][r] + bb);
        }
    }
    __syncthreads();
    const int b = (t0 - tokOffM) / Km, tokl = (t0 - tokOffM) - b * Km;
    const size_t vbase = (size_t)tokOffM * 512 + (size_t)b * 512 * Km + tokl;
    #pragma unroll
    for (int it = 0; it < 8; ++it){
      int flat = it * 256 + tid;
      int el = flat >> 4, tg = flat & 15;
      const u16* tp = T + el * 136 + tg * 8;
      int4 pk;
      pk.x = (int)((u32)tp[0] | ((u32)tp[1] << 16));
      pk.y = (int)((u32)tp[2] | ((u32)tp[3] << 16));
      pk.z = (int)((u32)tp[4] | ((u32)tp[5] << 16));
      pk.w = (int)((u32)tp[6] | ((u32)tp[7] << 16));
      *(int4*)(Vtb + vbase + (size_t)(colBase + el) * Km + tg * 8) = pk;
    }
  } else {
    const float scale = (widx == 0) ? 0.04419417382415922f : 1.0f;   // 1/sqrt(512) into Q
    #pragma unroll
    for (int ni = 0; ni < 4; ++ni){
      int col = colBase + wn * 64 + ni * 16 + c;
      float bb = bias[col];
      #pragma unroll
      for (int mi = 0; mi < 4; ++mi)
        #pragma unroll
        for (int r = 0; r < 4; ++r){
          int token = t0 + wm * 64 + mi * 16 + g * 4 + r;
          float val = (acc[mi][ni][r] + bb) * scale;
          size_t idx = (size_t)token * 512 + col;
          if (widx == 3)      outF[idx] = val;
          else if (widx == 0) Qb[idx] = f2bf(val);
          else                Kb[idx] = f2bf(val);
        }
    }
  }
}

// ---------------- kernel 2b: R12 proj (fallback when ws too small) ----------------
__global__ void __launch_bounds__(256, 2) proj_k(
    const float* __restrict__ E0, const float* __restrict__ E1, const float* __restrict__ E2,
    const u16* __restrict__ Wbf,
    const float* __restrict__ bq, const float* __restrict__ bk,
    const float* __restrict__ bv, const float* __restrict__ bo,
    u16* __restrict__ Qb, u16* __restrict__ Kb, u16* __restrict__ Vtb,
    float* __restrict__ outF)
{
  __shared__ __align__(16) char smem[65536];

  const int lin = blockIdx.x;
  const int swz = (lin & 7) * 1152 + (lin >> 3);
  const int mt = swz >> 4, nt = swz & 15;
  const int widx = nt >> 2, colBase = (nt & 3) * 128;
  const int t0 = mt * 128;
  const int mod = (t0 >= 57344) ? 2 : (t0 >= 32768) ? 1 : 0;
  const int tokOffM = (mod == 0) ? 0 : (mod == 1) ? 32768 : 57344;
  const int Km = (mod == 0) ? 1024 : (mod == 1) ? 768 : 512;
  const float* E = (mod == 0) ? E0 : (mod == 1) ? E1 : E2;
  const float* bias = (widx == 0) ? bq : (widx == 1) ? bk : (widx == 2) ? bv : bo;

  const int tid = threadIdx.x, wv = tid >> 6, l = tid & 63, g = l >> 4, c = l & 15;
  const int wm = wv >> 1, wn = wv & 1;

  float4 ar[4][2];
  vf4 acc[4][4];
  #pragma unroll
  for (int mi = 0; mi < 4; ++mi)
    #pragma unroll
    for (int ni = 0; ni < 4; ++ni) acc[mi][ni] = (vf4){0.f, 0.f, 0.f, 0.f};

  auto loadA = [&](int kt){
    #pragma unroll
    for (int p = 0; p < 4; ++p){
      int t = p * 256 + tid, row = t >> 3, sl = t & 7;
      const float* s = E + (size_t)(t0 - tokOffM + row) * 512 + kt * 64 + ((sl ^ (row & 7)) << 3);
      ar[p][0] = *(const float4*)s;
      ar[p][1] = *(const float4*)(s + 4);
    }
  };
  auto glB = [&](int kt, int nxt){
    char* dst = smem + 32768 + nxt * 16384;
    #pragma unroll
    for (int p = 0; p < 4; ++p){
      int t = p * 256 + tid, row = t >> 3, sl = t & 7;
      gll16(Wbf + (size_t)(nt * 128 + row) * 512 + kt * 64 + ((sl ^ (row & 7)) << 3),
            dst + t * 16);
    }
  };
  auto writeA = [&](int nxt){
    char* dst = smem + nxt * 16384;
    #pragma unroll
    for (int p = 0; p < 4; ++p){
      int t = p * 256 + tid;
      int4 pk;
      pk.x = (int)((u32)f2bf(ar[p][0].x) | ((u32)f2bf(ar[p][0].y) << 16));
      pk.y = (int)((u32)f2bf(ar[p][0].z) | ((u32)f2bf(ar[p][0].w) << 16));
      pk.z = (int)((u32)f2bf(ar[p][1].x) | ((u32)f2bf(ar[p][1].y) << 16));
      pk.w = (int)((u32)f2bf(ar[p][1].z) | ((u32)f2bf(ar[p][1].w) << 16));
      *(int4*)(dst + t * 16) = pk;
    }
  };

  loadA(0); glB(0, 0);
  asm volatile("s_waitcnt vmcnt(4)" ::: "memory");
  writeA(0);
  loadA(1);

  #pragma unroll
  for (int kt = 0; kt < 8; ++kt){
    const int cur = kt & 1;
    if (kt == 7) asm volatile("s_waitcnt vmcnt(0)" ::: "memory");
    else         asm volatile("s_waitcnt vmcnt(8)" ::: "memory");
    asm volatile("s_waitcnt lgkmcnt(0)" ::: "memory");
    __builtin_amdgcn_s_barrier();
    asm volatile("" ::: "memory");
    if (kt + 1 < 8) glB(kt + 1, cur ^ 1);

    const char* A  = smem + cur * 16384;
    const char* Bl = smem + 32768 + cur * 16384;
    #pragma unroll
    for (int kh = 0; kh < 2; ++kh){
      vbf8 af[4], bf[4];
      #pragma unroll
      for (int mi = 0; mi < 4; ++mi){
        int row = wm * 64 + mi * 16 + c;
        af[mi] = *(const vbf8*)(A + row * 128 + ((((kh << 2) + g) ^ (row & 7)) << 4));
      }
      #pragma unroll
      for (int ni = 0; ni < 4; ++ni){
        int row = wn * 64 + ni * 16 + c;
        bf[ni] = *(const vbf8*)(Bl + row * 128 + ((((kh << 2) + g) ^ (row & 7)) << 4));
      }
      #pragma unroll
      for (int mi = 0; mi < 4; ++mi)
        #pragma unroll
        for (int ni = 0; ni < 4; ++ni)
          acc[mi][ni] = MFMA(af[mi], bf[ni], acc[mi][ni]);
    }

    if (kt + 1 < 8){
      asm volatile("s_waitcnt vmcnt(4)" ::: "memory");
      writeA(cur ^ 1);
      if (kt + 2 < 8) loadA(kt + 2);
    }
  }
  __syncthreads();

  if (widx == 2){
    u16* T = (u16*)smem;
    #pragma unroll
    for (int ni = 0; ni < 4; ++ni){
      int el = wn * 64 + ni * 16 + c;
      float bb = bias[colBase + el];
      #pragma unroll
      for (int mi = 0; mi < 4; ++mi)
        #pragma unroll
        for (int r = 0; r < 4; ++r){
          int tk = wm * 64 + mi * 16 + g * 4 + r;
          T[el * 136 + tk] = f2bf(acc[mi][ni][r] + bb);
        }
    }
    __syncthreads();
    const int b = (t0 - tokOffM) / Km, tokl = (t0 - tokOffM) - b * Km;
    const size_t vbase = (size_t)tokOffM * 512 + (size_t)b * 512 * Km + tokl;
    #pragma unroll
    for (int it = 0; it < 8; ++it){
      int flat = it * 256 + tid;
      int el = flat >> 4, tg = flat & 15;
      const u16* tp = T + el * 136 + tg * 8;
      int4 pk;
      pk.x = (int)((u32)tp[0] | ((u32)tp[1] << 16));
      pk.y = (int)((u32)tp[2] | ((u32)tp[3] << 16));
      pk.z = (int)((u32)tp[4] | ((u32)tp[5] << 16));
      pk.w = (int)((u32)tp[6] | ((u32)tp[7] << 16));
      *(int4*)(Vtb + vbase + (size_t)(colBase + el) * Km + tg * 8) = pk;
    }
  } else {
    const float scale = (widx == 0) ? 0.04419417382415922f : 1.0f;
    #pragma unroll
    for (int ni = 0; ni < 4; ++ni){
      int col = colBase + wn * 64 + ni * 16 + c;
      float bb = bias[col];
      #pragma unroll
      for (int mi = 0; mi < 4; ++mi)
        #pragma unroll
        for (int r = 0; r < 4; ++r){
          int token = t0 + wm * 64 + mi * 16 + g * 4 + r;
          float val = (acc[mi][ni][r] + bb) * scale;
          size_t idx = (size_t)token * 512 + col;
          if (widx == 3)      outF[idx] = val;
          else if (widx == 0) Qb[idx] = f2bf(val);
          else                Kb[idx] = f2bf(val);
        }
    }
  }
}

// ---------------- kernel 3: cross attention (R12-exact + setprio) ----------------
__global__ void __launch_bounds__(512, 2) attn_k(
    const u16* __restrict__ Qb, const u16* __restrict__ Kb,
    const u16* __restrict__ Vtb, float* __restrict__ outF)
{
  __shared__ __align__(16) char smem[131072];  // K dbuf 2x32KB @0 | Vt dbuf 2x32KB @65536

  // XCD-balanced: 576 = 8 xcd * 72 (32 m0 | 24 m1 | 16 m2), y-locality per xcd
  const int lin = blockIdx.x;
  const int xcd = lin & 7, pos = lin >> 3;
  int m, y, xq;
  if (pos < 32)      { m = 0; y = xcd * 4 + (pos >> 3); xq = pos & 7; }
  else if (pos < 56) { int p = pos - 32; int yl = p / 6; m = 1; y = xcd * 4 + yl; xq = p - yl * 6; }
  else               { int p = pos - 56; m = 2; y = xcd * 4 + (p >> 2); xq = p & 3; }

  const int Km = (m == 0) ? 1024 : (m == 1) ? 768 : 512;
  const int tokOffM = (m == 0) ? 0 : (m == 1) ? 32768 : 57344;

  const int tid = threadIdx.x, wv = tid >> 6, l = tid & 63, g = l >> 4, c = l & 15;
  const int qbase = tokOffM + y * Km + xq * 128 + wv * 16;

  const int kperm = (c >> 2) * 8 + (c & 3);
  const int chx   = c >> 2;
  const int kb_lane = kperm * 1024 + ((g ^ (c & 3)) << 4);
  const int vb_lane = c * 64 + ((g ^ ((c >> 1) & 3)) << 4);

  vbf8 qf[16];
  {
    const u16* qp = Qb + (size_t)(qbase + c) * 512 + g * 8;
    #pragma unroll
    for (int ch = 0; ch < 16; ++ch) qf[ch] = *(const vbf8*)(qp + ch * 32);
  }

  vf4 acc[32];
  #pragma unroll
  for (int ch = 0; ch < 32; ++ch) acc[ch] = (vf4){0.f, 0.f, 0.f, 0.f};
  float lp = 0.f;

  for (int srcI = 0; srcI < 2; ++srcI){
    const int n = (srcI == 0) ? ((m == 0) ? 1 : 0) : ((m == 2) ? 1 : 2);
    const int Kn = (n == 0) ? 1024 : (n == 1) ? 768 : 512;
    const int NT = Kn >> 5;
    const int tokOffN = (n == 0) ? 0 : (n == 1) ? 32768 : 57344;
    const size_t kRow0 = (size_t)(tokOffN + y * Kn);
    const size_t vBase = (size_t)tokOffN * 512 + (size_t)y * 512 * Kn;

    auto stageK = [&](int kt, int buf){
      char* kd = smem + buf * 32768;
      const size_t kB = (kRow0 + kt * 32) * 512;
      #pragma unroll
      for (int p = 0; p < 4; ++p){
        int t = p * 512 + tid;
        int key = t >> 6, sl = t & 63;
        int F = (key & 3) | (((key >> 3) & 3) << 2);
        gll16(Kb + kB + (size_t)key * 512 + ((sl ^ F) << 3), kd + t * 16);
      }
    };
    auto stageV = [&](int kt, int buf){
      char* vd = smem + 65536 + buf * 32768;
      #pragma unroll
      for (int p = 0; p < 4; ++p){
        int t = p * 512 + tid;
        int d = t >> 2, sl = t & 3;
        gll16(Vtb + vBase + (size_t)d * Kn + kt * 32 + ((sl ^ ((d >> 1) & 3)) << 3),
              vd + t * 16);
      }
    };

    stageK(0, 0); stageV(0, 0);
    for (int kt = 0; kt < NT; ++kt){
      const int cur = kt & 1;
      asm volatile("s_waitcnt vmcnt(4)" ::: "memory");   // K(kt) landed (V(kt) may fly)
      __builtin_amdgcn_s_barrier();
      asm volatile("" ::: "memory");
      if (kt + 1 < NT) stageK(kt + 1, cur ^ 1);

      const char* kbuf = smem + cur * 32768;
      vf4 s0a = (vf4){0.f,0.f,0.f,0.f}, s0b = (vf4){0.f,0.f,0.f,0.f};
      vf4 s1a = (vf4){0.f,0.f,0.f,0.f}, s1b = (vf4){0.f,0.f,0.f,0.f};
      __builtin_amdgcn_s_setprio(1);
      #pragma unroll
      for (int ch = 0; ch < 8; ++ch){
        const char* pa0 = kbuf + kb_lane + ((ch ^ chx) << 6);
        const char* pa1 = kbuf + kb_lane + (((ch + 8) ^ chx) << 6);
        vbf8 ka0  = *(const vbf8*)(pa0);
        vbf8 ka0h = *(const vbf8*)(pa0 + 4096);
        vbf8 ka1  = *(const vbf8*)(pa1);
        vbf8 ka1h = *(const vbf8*)(pa1 + 4096);
        s0a = MFMA(ka0,  qf[ch],     s0a);
        s1a = MFMA(ka0h, qf[ch],     s1a);
        s0b = MFMA(ka1,  qf[ch + 8], s0b);
        s1b = MFMA(ka1h, qf[ch + 8], s1b);
      }
      __builtin_amdgcn_s_setprio(0);
      vf4 s0 = s0a + s0b, s1 = s1a + s1b;

      if (kt + 1 < NT) asm volatile("s_waitcnt vmcnt(4)" ::: "memory");
      else             asm volatile("s_waitcnt vmcnt(0)" ::: "memory");
      if (kt + 1 < NT) stageV(kt + 1, cur ^ 1);

      float e00 = __expf(s0[0]), e01 = __expf(s0[1]), e02 = __expf(s0[2]), e03 = __expf(s0[3]);
      float e10 = __expf(s1[0]), e11 = __expf(s1[1]), e12 = __expf(s1[2]), e13 = __expf(s1[3]);
      lp += (e00 + e01 + e02 + e03) + (e10 + e11 + e12 + e13);
      vbf8 pb;
      pb[0]=(short)f2bf(e00); pb[1]=(short)f2bf(e01); pb[2]=(short)f2bf(e02); pb[3]=(short)f2bf(e03);
      pb[4]=(short)f2bf(e10); pb[5]=(short)f2bf(e11); pb[6]=(short)f2bf(e12); pb[7]=(short)f2bf(e13);
      const char* vbuf = smem + 65536 + cur * 32768;
      __builtin_amdgcn_s_setprio(1);
      #pragma unroll
      for (int ch = 0; ch < 32; ++ch){
        vbf8 va = *(const vbf8*)(vbuf + vb_lane + ch * 1024);
        acc[ch] = MFMA(va, pb, acc[ch]);
      }
      __builtin_amdgcn_s_setprio(0);
      asm volatile("" ::: "memory");
    }
    __syncthreads();

    float t = lp;
    t += __shfl_xor(t, 16);
    t += __shfl_xor(t, 32);
    const float w = 1.0f / t;
    lp = 0.f;
    float* op = outF + (size_t)(qbase + c) * 512 + g * 4;
    #pragma unroll
    for (int ch = 0; ch < 32; ++ch){
      float4* p4 = (float4*)(op + ch * 16);
      float4 v = *p4;
      v.x += acc[ch][0] * w; v.y += acc[ch][1] * w;
      v.z += acc[ch][2] * w; v.w += acc[ch][3] * w;
      if (srcI == 1){
        v.x = fmaxf(v.x, 0.f); v.y = fmaxf(v.y, 0.f);
        v.z = fmaxf(v.z, 0.f); v.w = fmaxf(v.w, 0.f);
      }
      *p4 = v;
      acc[ch] = (vf4){0.f, 0.f, 0.f, 0.f};
    }
  }
}

// ---------------- host launcher ----------------
extern "C" void kernel_launch(void* const* d_in, const int* in_sizes, int n_in,
                              void* d_out, int out_size, void* d_ws, size_t ws_size,
                              hipStream_t stream){
  const float* E0 = (const float*)d_in[0];
  const float* E1 = (const float*)d_in[1];
  const float* E2 = (const float*)d_in[2];
  const float* Wq = (const float*)d_in[3];
  const float* bq = (const float*)d_in[4];
  const float* Wk = (const float*)d_in[5];
  const float* bk = (const float*)d_in[6];
  const float* Wv = (const float*)d_in[7];
  const float* bv = (const float*)d_in[8];
  const float* Wo = (const float*)d_in[9];
  const float* bo = (const float*)d_in[10];
  float* outF = (float*)d_out;

  char* ws = (char*)d_ws;
  const size_t SZ = 75497472u;                 // 73728*512*2 bytes (bf16)
  u16* Wbf = (u16*)ws;                         // 2 MB, [2048][512]
  u16* Qb  = (u16*)(ws + (size_t)(2u << 20));
  u16* Kb  = (u16*)(ws + (size_t)(2u << 20) + SZ);
  u16* Vtb = (u16*)(ws + (size_t)(2u << 20) + 2 * SZ);
  u16* Eb  = (u16*)(ws + (size_t)(2u << 20) + 3 * SZ);   // fast path only
  const size_t NEED_FAST = (size_t)(2u << 20) + 4 * SZ;  // ~290 MB

  if (ws_size >= NEED_FAST){
    conv_all_k<<<dim3(18944), dim3(256), 0, stream>>>(E0, E1, E2, Wq, Wk, Wv, Wo, Wbf, Eb);
    proj_fast_k<<<dim3(9216), dim3(256), 0, stream>>>(Eb, Wbf, bq, bk, bv, bo,
                                                      Qb, Kb, Vtb, outF);
  } else {
    wconv_k<<<dim3(1024), dim3(256), 0, stream>>>(Wq, Wk, Wv, Wo, Wbf);
    proj_k<<<dim3(9216), dim3(256), 0, stream>>>(E0, E1, E2, Wbf, bq, bk, bv, bo,
                                                 Qb, Kb, Vtb, outF);
  }
  attn_k<<<dim3(576), dim3(512), 0, stream>>>(Qb, Kb, Vtb, outF);
}